// Round 1
// 1210.373 us; speedup vs baseline: 1.0004x; 1.0004x over previous
//
#include <hip/hip_runtime.h>

// Problem constants
#define B_  16384
#define D_  1024
#define H_  512
#define E_  8
#define GH_ 128

typedef __fp16 h2  __attribute__((ext_vector_type(2)));
typedef __fp16 h8  __attribute__((ext_vector_type(8)));
typedef float  f4v __attribute__((ext_vector_type(4)));

#define BM  128
#define BN  128
#define BK  32
#define LDP 40   // padded LDS row stride (halfs): 80 B rows -> 8 distinct start banks, 2-way max

union HU { h2 h[4]; h8 v; };

__device__ __forceinline__ unsigned asu(h2 x) { return __builtin_bit_cast(unsigned, x); }

// ---------------------------------------------------------------------------
// Generic tiled f32-in MFMA GEMM used for the small precompute GEMMs.
// A: M x K row-major (lda), B: K x N row-major (ldb), batched via blockIdx.z.
// MODE 0: C fp32 (ldc), optional +bias then relu (RB).
// MODE 1: C stored transposed as f16: Ct[n][e*mStride + m], row stride ldt.
// ---------------------------------------------------------------------------
template<int MODE, bool RB>
__global__ __launch_bounds__(256, 3)
void gemm_pre(const float* __restrict__ A, long sA, int lda,
              const float* __restrict__ Bm, long sB, int ldb, int K,
              float* __restrict__ Cf, long sC, int ldc,
              const float* __restrict__ bias,
              __fp16* __restrict__ Ct, int ldt, int mStride)
{
    __shared__ __fp16 As[BM * LDP];
    __shared__ __fp16 Bs[BN * LDP];
    const int t    = threadIdx.x;
    const int bm0  = blockIdx.x * BM;
    const int n0   = blockIdx.y * BN;
    const int e    = blockIdx.z;
    A  += (long)e * sA;
    Bm += (long)e * sB;

    const int lane = t & 63, w = t >> 6, quad = lane >> 4, l16 = lane & 15;
    const int wrow = w & 1, wcol = w >> 1;

    // A staging: thread -> (row = t>>1, 16-float chunk = t&1)
    const int arow = t >> 1, ach = t & 1;
    const float* aSrc = A + (long)(bm0 + arow) * lda + ach * 16;
    __fp16* aDst = &As[arow * LDP + ach * 16];

    // B staging: 4x4 fp32 sub-block transpose. thread -> (kb = t>>5 in 0..7, nb = t&31)
    const int kb = t >> 5, nb = t & 31;
    const float* bSrc = Bm + (long)(kb * 4) * ldb + n0 + nb * 4;
    __fp16* bDst = &Bs[(nb * 4) * LDP + kb * 4];

    f4v acc[4][4] = {};

    const int ksteps = K / BK;
    for (int ks = 0; ks < ksteps; ++ks) {
        const float* ap = aSrc + ks * BK;
        f4v a0 = *(const f4v*)(ap);
        f4v a1 = *(const f4v*)(ap + 4);
        f4v a2 = *(const f4v*)(ap + 8);
        f4v a3 = *(const f4v*)(ap + 12);
        const float* bp = bSrc + (long)ks * BK * ldb;
        f4v r0 = *(const f4v*)(bp);
        f4v r1 = *(const f4v*)(bp + ldb);
        f4v r2 = *(const f4v*)(bp + 2 * ldb);
        f4v r3 = *(const f4v*)(bp + 3 * ldb);

        __syncthreads();   // previous iteration's frag reads complete

        HU u0, u1;
        u0.h[0] = __builtin_amdgcn_cvt_pkrtz(a0.x, a0.y);
        u0.h[1] = __builtin_amdgcn_cvt_pkrtz(a0.z, a0.w);
        u0.h[2] = __builtin_amdgcn_cvt_pkrtz(a1.x, a1.y);
        u0.h[3] = __builtin_amdgcn_cvt_pkrtz(a1.z, a1.w);
        u1.h[0] = __builtin_amdgcn_cvt_pkrtz(a2.x, a2.y);
        u1.h[1] = __builtin_amdgcn_cvt_pkrtz(a2.z, a2.w);
        u1.h[2] = __builtin_amdgcn_cvt_pkrtz(a3.x, a3.y);
        u1.h[3] = __builtin_amdgcn_cvt_pkrtz(a3.z, a3.w);
        *(h8*)aDst       = u0.v;
        *(h8*)(aDst + 8) = u1.v;

        // 4x4 in-register transpose of B into Bs[n][k]
        h2 P0 = __builtin_amdgcn_cvt_pkrtz(r0.x, r0.y);
        h2 P1 = __builtin_amdgcn_cvt_pkrtz(r1.x, r1.y);
        h2 P2 = __builtin_amdgcn_cvt_pkrtz(r2.x, r2.y);
        h2 P3 = __builtin_amdgcn_cvt_pkrtz(r3.x, r3.y);
        h2 Q0 = __builtin_amdgcn_cvt_pkrtz(r0.z, r0.w);
        h2 Q1 = __builtin_amdgcn_cvt_pkrtz(r1.z, r1.w);
        h2 Q2 = __builtin_amdgcn_cvt_pkrtz(r2.z, r2.w);
        h2 Q3 = __builtin_amdgcn_cvt_pkrtz(r3.z, r3.w);
        // (X.lo,Y.lo): perm(Y, X, 0x05040100) ; (X.hi,Y.hi): perm(Y, X, 0x07060302)
        uint2 c0 = make_uint2(__builtin_amdgcn_perm(asu(P1), asu(P0), 0x05040100),
                              __builtin_amdgcn_perm(asu(P3), asu(P2), 0x05040100));
        uint2 c1 = make_uint2(__builtin_amdgcn_perm(asu(P1), asu(P0), 0x07060302),
                              __builtin_amdgcn_perm(asu(P3), asu(P2), 0x07060302));
        uint2 c2 = make_uint2(__builtin_amdgcn_perm(asu(Q1), asu(Q0), 0x05040100),
                              __builtin_amdgcn_perm(asu(Q3), asu(Q2), 0x05040100));
        uint2 c3 = make_uint2(__builtin_amdgcn_perm(asu(Q1), asu(Q0), 0x07060302),
                              __builtin_amdgcn_perm(asu(Q3), asu(Q2), 0x07060302));
        *(uint2*)(bDst)           = c0;
        *(uint2*)(bDst + LDP)     = c1;
        *(uint2*)(bDst + 2 * LDP) = c2;
        *(uint2*)(bDst + 3 * LDP) = c3;

        __syncthreads();   // staging visible

        h8 af[4], bf[4];
        #pragma unroll
        for (int i = 0; i < 4; ++i)
            af[i] = *(const h8*)&As[(wrow * 64 + i * 16 + l16) * LDP + quad * 8];
        #pragma unroll
        for (int j = 0; j < 4; ++j)
            bf[j] = *(const h8*)&Bs[(wcol * 64 + j * 16 + l16) * LDP + quad * 8];
        #pragma unroll
        for (int i = 0; i < 4; ++i) {
            #pragma unroll
            for (int j = 0; j < 4; ++j)
                acc[i][j] = __builtin_amdgcn_mfma_f32_16x16x32_f16(af[i], bf[j], acc[i][j], 0, 0, 0);
        }
    }

    if constexpr (MODE == 0) {
        float* C = Cf + (long)e * sC;
        #pragma unroll
        for (int j = 0; j < 4; ++j) {
            const int cg = n0 + wcol * 64 + j * 16 + l16;
            float bb = 0.f;
            if constexpr (RB) bb = bias[cg];
            #pragma unroll
            for (int i = 0; i < 4; ++i) {
                const int rb = bm0 + wrow * 64 + i * 16 + quad * 4;
                #pragma unroll
                for (int r = 0; r < 4; ++r) {
                    float v = acc[i][j][r] + bb;
                    if constexpr (RB) v = fmaxf(v, 0.f);
                    C[(long)(rb + r) * ldc + cg] = v;
                }
            }
        }
    } else {
        #pragma unroll
        for (int j = 0; j < 4; ++j) {
            const int n = n0 + wcol * 64 + j * 16 + l16;
            #pragma unroll
            for (int i = 0; i < 4; ++i) {
                const int m = e * mStride + bm0 + wrow * 64 + i * 16 + quad * 4;
                union { h2 hh[2]; uint2 u; } up;
                up.hh[0] = __builtin_amdgcn_cvt_pkrtz(acc[i][j][0], acc[i][j][1]);
                up.hh[1] = __builtin_amdgcn_cvt_pkrtz(acc[i][j][2], acc[i][j][3]);
                *(uint2*)&Ct[(long)n * ldt + m] = up.u;
            }
        }
    }
}

// ---------------------------------------------------------------------------
// bc[e,h] = bo[e,h] + sum_g bv[e,g]*VmO[e,g,h] + sum_g bvm[e,g]*Wo[e,g,h]
// ---------------------------------------------------------------------------
__global__ void k_bc(const float* __restrict__ bv, const float* __restrict__ bvm,
                     const float* __restrict__ bo, const float* __restrict__ Wo,
                     const float* __restrict__ VmO, float* __restrict__ bc)
{
    const int idx = blockIdx.x * 256 + threadIdx.x;   // 0..4095
    const int e = idx >> 9, h = idx & 511;
    const float* vmo = VmO + (long)e * H_ * H_ + h;
    const float* wo  = Wo  + (long)e * H_ * H_ + h;
    const float* bve  = bv  + e * H_;
    const float* bvme = bvm + e * H_;
    float s = bo[e * H_ + h];
    for (int g = 0; g < H_; ++g)
        s += bve[g] * vmo[(long)g * H_] + bvme[g] * wo[(long)g * H_];
    bc[e * H_ + h] = s;
}

// ---------------------------------------------------------------------------
// gate[b,:] = softmax(H1[b,:] @ Wg2 + bg2), 64 rows per block
// ---------------------------------------------------------------------------
__global__ __launch_bounds__(256)
void k_gate(const float* __restrict__ H1, const float* __restrict__ Wg2,
            const float* __restrict__ bg2, float* __restrict__ gate)
{
    __shared__ float Wg2s[GH_ * E_];
    __shared__ float Lg[64][E_];
    const int t = threadIdx.x;
    *(f4v*)&Wg2s[t * 4] = *(const f4v*)&Wg2[t * 4];
    __syncthreads();

    const int r = t & 63, e2 = t >> 6;     // e2 in 0..3, handles experts 2*e2, 2*e2+1
    const int row = blockIdx.x * 64 + r;
    const int e0 = e2 * 2;
    const f4v* h4 = (const f4v*)(H1 + (long)row * GH_);
    float l0 = bg2[e0], l1 = bg2[e0 + 1];
    for (int g4 = 0; g4 < GH_ / 4; ++g4) {
        f4v hv = h4[g4];
        const int gb = g4 * 4 * E_;
        l0 += hv.x * Wg2s[gb + e0]      + hv.y * Wg2s[gb + 8 + e0]
            + hv.z * Wg2s[gb + 16 + e0] + hv.w * Wg2s[gb + 24 + e0];
        l1 += hv.x * Wg2s[gb + e0 + 1]      + hv.y * Wg2s[gb + 8 + e0 + 1]
            + hv.z * Wg2s[gb + 16 + e0 + 1] + hv.w * Wg2s[gb + 24 + e0 + 1];
    }
    Lg[r][e0] = l0; Lg[r][e0 + 1] = l1;
    __syncthreads();
    if (t < 64) {
        float m = Lg[t][0];
        #pragma unroll
        for (int e = 1; e < E_; ++e) m = fmaxf(m, Lg[t][e]);
        float ex[E_], s = 0.f;
        #pragma unroll
        for (int e = 0; e < E_; ++e) { ex[e] = __expf(Lg[t][e] - m); s += ex[e]; }
        const float inv = 1.f / s;
        float* gr = gate + (long)(blockIdx.x * 64 + t) * E_;
        #pragma unroll
        for (int e = 0; e < E_; ++e) gr[e] = ex[e] * inv;
    }
}

// ---------------------------------------------------------------------------
// Main GEMM: out[b,h] = sum_{e,d} gate[b,e]*freq[e,b,d]*WcT[h, e*1024+d]
//                       + sum_e gate[b,e]*bc[e,h]
// M=16384, N=512, K=8192. A scaled+converted fp32->f16 during staging.
// grid(128,4): the 4 N-tiles of an M-tile share (id mod 8) -> same XCD L2.
//
// Latency-bound fix (this revision): double-buffered LDS, ONE barrier per
// K-step, 2-deep register prefetch (loads for tile ks+2 issued at step ks),
// and lgkmcnt-only barriers (no vmcnt(0) drain: all global loads land in
// registers, so no cross-wave VMEM visibility is needed; the compiler's
// use-driven vmcnt(N) waits cover the reg loads precisely).
// ---------------------------------------------------------------------------

// lgkmcnt(0): staged ds_writes visible before barrier. No vmcnt drain.
#define SYNC() asm volatile("s_waitcnt lgkmcnt(0)\ns_barrier" ::: "memory")

#define ISSUE(k, aR, wR) do {                                                  \
    const int e_ = (k) >> 5;                                                   \
    const float* ap_ = aBase + (long)e_ * ((long)B_ * D_) + ((k) & 31) * BK;   \
    aR[0] = *(const f4v*)(ap_);                                                \
    aR[1] = *(const f4v*)(ap_ + 4);                                            \
    aR[2] = *(const f4v*)(ap_ + 8);                                            \
    aR[3] = *(const f4v*)(ap_ + 12);                                           \
    const __fp16* wp_ = wBase + (long)(k) * BK;                                \
    wR[0] = *(const h8*)(wp_);                                                 \
    wR[1] = *(const h8*)(wp_ + 8);                                             \
} while (0)

#define STAGE(half, aR, wR, gvv) do {                                          \
    const __fp16 gs_ = (__fp16)(gvv);                                          \
    const h2 gh_ = {gs_, gs_};                                                 \
    HU u0_, u1_;                                                               \
    u0_.h[0] = __builtin_amdgcn_cvt_pkrtz(aR[0].x, aR[0].y) * gh_;             \
    u0_.h[1] = __builtin_amdgcn_cvt_pkrtz(aR[0].z, aR[0].w) * gh_;             \
    u0_.h[2] = __builtin_amdgcn_cvt_pkrtz(aR[1].x, aR[1].y) * gh_;             \
    u0_.h[3] = __builtin_amdgcn_cvt_pkrtz(aR[1].z, aR[1].w) * gh_;             \
    u1_.h[0] = __builtin_amdgcn_cvt_pkrtz(aR[2].x, aR[2].y) * gh_;             \
    u1_.h[1] = __builtin_amdgcn_cvt_pkrtz(aR[2].z, aR[2].w) * gh_;             \
    u1_.h[2] = __builtin_amdgcn_cvt_pkrtz(aR[3].x, aR[3].y) * gh_;             \
    u1_.h[3] = __builtin_amdgcn_cvt_pkrtz(aR[3].z, aR[3].w) * gh_;             \
    __fp16* ad_ = aDst + (half) * (BM * LDP);                                  \
    *(h8*)ad_       = u0_.v;                                                   \
    *(h8*)(ad_ + 8) = u1_.v;                                                   \
    __fp16* bd_ = bDst + (half) * (BM * LDP);                                  \
    *(h8*)bd_       = wR[0];                                                   \
    *(h8*)(bd_ + 8) = wR[1];                                                   \
} while (0)

#define COMPUTE(half) do {                                                     \
    const __fp16* As_ = As + (half) * (BM * LDP);                              \
    const __fp16* Bs_ = Bs + (half) * (BM * LDP);                              \
    h8 af[4], bf[4];                                                           \
    _Pragma("unroll")                                                          \
    for (int i = 0; i < 4; ++i)                                                \
        af[i] = *(const h8*)&As_[(wrow * 64 + i * 16 + l16) * LDP + quad * 8]; \
    _Pragma("unroll")                                                          \
    for (int j = 0; j < 4; ++j)                                                \
        bf[j] = *(const h8*)&Bs_[(wcol * 64 + j * 16 + l16) * LDP + quad * 8]; \
    _Pragma("unroll")                                                          \
    for (int i = 0; i < 4; ++i) {                                              \
        _Pragma("unroll")                                                      \
        for (int j = 0; j < 4; ++j)                                            \
            acc[i][j] = __builtin_amdgcn_mfma_f32_16x16x32_f16(af[i], bf[j], acc[i][j], 0, 0, 0); \
    }                                                                          \
} while (0)

__global__ __launch_bounds__(256, 2)
void k_main(const float* __restrict__ freq, const float* __restrict__ gate,
            const __fp16* __restrict__ WcT, const float* __restrict__ bc,
            float* __restrict__ out)
{
    __shared__ __fp16 As[2 * BM * LDP];
    __shared__ __fp16 Bs[2 * BM * LDP];
    __shared__ float gateS[BM * E_];
    __shared__ float bcS[E_ * BN];

    const int t    = threadIdx.x;
    const int bm0  = blockIdx.x * BM;
    const int n0   = blockIdx.y * BN;
    const int lane = t & 63, w = t >> 6, quad = lane >> 4, l16 = lane & 15;
    const int wrow = w & 1, wcol = w >> 1;

    const int arow = t >> 1, ach = t & 1;
    const int brow = bm0 + arow;
    const float*  aBase = freq + (long)brow * D_ + ach * 16;
    const __fp16* wBase = WcT + (long)(n0 + arow) * (E_ * D_) + ach * 16;
    __fp16* aDst = &As[arow * LDP + ach * 16];
    __fp16* bDst = &Bs[arow * LDP + ach * 16];

    f4v acc[4][4] = {};

    const int NK = (E_ * D_) / BK;   // 256 (even)

    // two named prefetch register sets (NO runtime-indexed arrays -> no scratch)
    f4v aE[4], aO[4];
    h8  wE[2], wO[2];

    // prologue: issue tiles 0,1; stage tile 0 into buffer 0
    ISSUE(0, aE, wE);
    ISSUE(1, aO, wO);
    float gv    = gate[brow * E_ + 0];   // expert 0
    float gNext = 0.f;
    STAGE(0, aE, wE, gv);
    SYNC();

    for (int ks = 0; ks < NK; ks += 2) {
        // ---- half A: compute tile ks (buf0); stage tile ks+1 (buf1); issue ks+2
        if (ks + 2 < NK) {                         // wave-uniform
            ISSUE(ks + 2, aE, wE);
            if (((ks + 2) & 31) == 0)              // expert boundary: prefetch gate
                gNext = gate[brow * E_ + ((ks + 2) >> 5)];
        }
        COMPUTE(0);
        // ks+1 is odd -> never crosses an expert boundary -> gv is correct
        STAGE(1, aO, wO, gv);
        SYNC();

        // ---- half B: compute tile ks+1 (buf1); stage tile ks+2 (buf0); issue ks+3
        if (ks + 3 < NK) {                         // ks+3 odd -> no gate reload needed
            ISSUE(ks + 3, aO, wO);
        }
        COMPUTE(1);
        if (ks + 2 < NK) {
            if (((ks + 2) & 31) == 0) gv = gNext;  // consume prefetched gate
            STAGE(0, aE, wE, gv);
        }
        SYNC();
    }

    // epilogue: bias = gate[b,:] . bc[:,h] via LDS-staged gate rows + bc cols
    *(f4v*)&gateS[t * 4] = *(const f4v*)&gate[(long)bm0 * E_ + t * 4];
    *(f4v*)&bcS[t * 4]   = *(const f4v*)&bc[(t >> 5) * H_ + n0 + (t & 31) * 4];
    __syncthreads();

    #pragma unroll
    for (int j = 0; j < 4; ++j) {
        const int cl = wcol * 64 + j * 16 + l16;
        float bv8[E_];
        #pragma unroll
        for (int e = 0; e < E_; ++e) bv8[e] = bcS[e * BN + cl];
        #pragma unroll
        for (int i = 0; i < 4; ++i) {
            const int rl = wrow * 64 + i * 16 + quad * 4;
            #pragma unroll
            for (int r = 0; r < 4; ++r) {
                const float* gr = &gateS[(rl + r) * E_];
                float bias = 0.f;
                #pragma unroll
                for (int e = 0; e < E_; ++e) bias += gr[e] * bv8[e];
                out[(long)(bm0 + rl + r) * H_ + (n0 + cl)] = acc[i][j][r] + bias;
            }
        }
    }
}

// ---------------------------------------------------------------------------
extern "C" void kernel_launch(void* const* d_in, const int* in_sizes, int n_in,
                              void* d_out, int out_size, void* d_ws, size_t ws_size,
                              hipStream_t stream)
{
    const float* freq = (const float*)d_in[0];
    const float* sem  = (const float*)d_in[1];
    // d_in[2..5]: Wq,bq,Wk,bk (dead: softmax over 1 key == 1)
    const float* Wv   = (const float*)d_in[6];
    const float* bv   = (const float*)d_in[7];
    // d_in[8..11]: Wqm,bqm,Wkm,bkm (dead)
    const float* Wvm  = (const float*)d_in[12];
    const float* bvm  = (const float*)d_in[13];
    const float* Wo   = (const float*)d_in[14];
    const float* bo   = (const float*)d_in[15];
    const float* Wg1  = (const float*)d_in[16];
    const float* bg1  = (const float*)d_in[17];
    const float* Wg2  = (const float*)d_in[18];
    const float* bg2  = (const float*)d_in[19];
    float* out = (float*)d_out;

    char* ws = (char*)d_ws;
    float*   VmO  = (float*)ws;                                  //  8 MB: E x 512 x 512 f32
    __fp16*  WcT  = (__fp16*)(ws + (8l << 20));                  //  8 MB: 512 x 8192 f16
    float*   bc   = (float*)(ws + (16l << 20));                  // 16 KB (padded to 64 KB)
    float*   H1   = (float*)(ws + (16l << 20) + (1l << 16));     //  8 MB: B x 128 f32
    float*   gate = (float*)(ws + (24l << 20) + (1l << 16));     // 512 KB: B x 8 f32

    // 1) VmO[e] = Wvm[e] @ Wo[e]                  (M=512, K=512, N=512)
    gemm_pre<0, false><<<dim3(4, 4, 8), 256, 0, stream>>>(
        Wvm, (long)H_ * H_, H_, Wo, (long)H_ * H_, H_, H_,
        VmO, (long)H_ * H_, H_, nullptr, nullptr, 0, 0);

    // 2) bc[e] = bv@VmO + bvm@Wo + bo
    k_bc<<<16, 256, 0, stream>>>(bv, bvm, bo, Wo, VmO, bc);

    // 3) WcT[h, e*1024+d] = f16( (Wv[e] @ VmO[e])[d,h] )   (M=1024, K=512, N=512)
    gemm_pre<1, false><<<dim3(8, 4, 8), 256, 0, stream>>>(
        Wv, (long)D_ * H_, H_, VmO, (long)H_ * H_, H_, H_,
        nullptr, 0, 0, nullptr, WcT, E_ * D_, D_);

    // 4) H1 = relu(sem @ Wg1 + bg1)              (M=16384, K=1024, N=128)
    gemm_pre<0, true><<<dim3(128, 1, 1), 256, 0, stream>>>(
        sem, 0, D_, Wg1, 0, GH_, D_,
        H1, 0, GH_, bg1, nullptr, 0, 0);

    // 5) gate = softmax(H1 @ Wg2 + bg2)
    k_gate<<<256, 256, 0, stream>>>(H1, Wg2, bg2, gate);

    // 6) fused = gated single GEMM over stacked experts + gated bias
    k_main<<<dim3(128, 4), 256, 0, stream>>>(freq, gate, WcT, bc, out);
}